// Round 7
// baseline (116.543 us; speedup 1.0000x reference)
//
#include <hip/hip_runtime.h>

// CollisionLoss: loss = sum_{b,t,n} relu(tx[b,n] - |ex[b,t]-cx[b,n]|)
//                              * relu(ty[b,n] - |ey[b,t]-cy[b,n]|) * valid
//                / max(sum(ego_mask>=1), 1)
// pred_abs (B,T,2) f32, gt_bboxes (B,N,9) f32, ego_masks (B,T) i32,
// agent_mask (B,N) i32. B=4096, T=12, N=512.
//
// R1: same-address atomics serialized (153us). R2-R4: 21-23us, insensitive
// to load structure (scalar vs staged vs fat upfront) -> line-movement or
// overhead bound. R6: cooperative launch not graph-capturable (empty graph,
// out=0). R7: last-block finisher with scoped atomics (one atomicAdd per
// block, staggered -> no serialization), 4B memset for the counter.

#define T_DIM 12
#define N_DIM 512

typedef float f32x4 __attribute__((ext_vector_type(4)));

__global__ __launch_bounds__(256) void collision_loss_fused(
    const float* __restrict__ pred_abs,   // (B,T,2)
    const float* __restrict__ gt_bboxes,  // (B,N,9)
    const int*   __restrict__ ego_masks,  // (B,T)
    const int*   __restrict__ agent_mask, // (B,N)
    unsigned long long* __restrict__ ws_part, // (grid) packed float2 partials
    int*   __restrict__ ws_flag,          // completion counter (zeroed per call)
    float* __restrict__ out)              // scalar result
{
    __shared__ float s_ex[2][T_DIM];
    __shared__ float s_ey[2][T_DIM];
    __shared__ float s_part[4];
    __shared__ float s_l[4], s_c[4];
    __shared__ int   s_last;

    const int b0  = blockIdx.x * 2;       // this block owns batches b0, b0+1
    const int tid = threadIdx.x;

    // ---- Ego staging (both batches); invalid ego -> +1e30 => term 0 ----
    int ev = 0;
    if (tid < 2 * T_DIM) {                // lanes 0..23 of wave 0
        const int bb = tid / T_DIM;
        const int t  = tid % T_DIM;
        const int b  = b0 + bb;
        ev = (ego_masks[b * T_DIM + t] >= 1) ? 1 : 0;
        const float ex = pred_abs[(b * T_DIM + t) * 2 + 0];
        const float ey = pred_abs[(b * T_DIM + t) * 2 + 1];
        s_ex[bb][t] = ev ? ex : 1e30f;
        s_ey[bb][t] = ev ? ey : 1e30f;
    }
    const float cnt = (float)__popcll(__ballot(ev != 0)); // wave-0 value used

    // ---- 4 agents/thread: nontemporal dwordx4 + dword, issued upfront ----
    const float* base = gt_bboxes + (size_t)b0 * (N_DIM * 9);
    const f32x4 f0 = __builtin_nontemporal_load(
        (const f32x4*)(base + (size_t)(tid      ) * 9));
    const float g0 = __builtin_nontemporal_load(base + (size_t)(tid      ) * 9 + 4);
    const f32x4 f1 = __builtin_nontemporal_load(
        (const f32x4*)(base + (size_t)(tid + 256) * 9));
    const float g1 = __builtin_nontemporal_load(base + (size_t)(tid + 256) * 9 + 4);
    const f32x4 f2 = __builtin_nontemporal_load(
        (const f32x4*)(base + (size_t)(tid + 512) * 9));
    const float g2 = __builtin_nontemporal_load(base + (size_t)(tid + 512) * 9 + 4);
    const f32x4 f3 = __builtin_nontemporal_load(
        (const f32x4*)(base + (size_t)(tid + 768) * 9));
    const float g3 = __builtin_nontemporal_load(base + (size_t)(tid + 768) * 9 + 4);

    const int* am = agent_mask + b0 * N_DIM;
    const int av0 = __builtin_nontemporal_load(am + tid)       >= 1;
    const int av1 = __builtin_nontemporal_load(am + tid + 256) >= 1;
    const int av2 = __builtin_nontemporal_load(am + tid + 512) >= 1;
    const int av3 = __builtin_nontemporal_load(am + tid + 768) >= 1;

    // Invalid agent -> tx = -1e30 => relu term 0 (branch-free loop).
    const float tx0 = av0 ? (1.175f + f0.w * 0.5f + 1.5f) : -1e30f;
    const float tx1 = av1 ? (1.175f + f1.w * 0.5f + 1.5f) : -1e30f;
    const float tx2 = av2 ? (1.175f + f2.w * 0.5f + 1.5f) : -1e30f;
    const float tx3 = av3 ? (1.175f + f3.w * 0.5f + 1.5f) : -1e30f;
    const float ty0 = 2.292f + g0 * 0.5f + 1.5f;
    const float ty1 = 2.292f + g1 * 0.5f + 1.5f;
    const float ty2 = 2.292f + g2 * 0.5f + 1.5f;
    const float ty3 = 2.292f + g3 * 0.5f + 1.5f;

    __syncthreads();   // ego staged

    float acc = 0.0f;
    #pragma unroll
    for (int t = 0; t < T_DIM; ++t) {
        const float exA = s_ex[0][t], eyA = s_ey[0][t];
        const float exB = s_ex[1][t], eyB = s_ey[1][t];
        const float px0 = fmaxf(tx0 - fabsf(exA - f0.x), 0.0f);
        const float py0 = fmaxf(ty0 - fabsf(eyA - f0.y), 0.0f);
        const float px1 = fmaxf(tx1 - fabsf(exA - f1.x), 0.0f);
        const float py1 = fmaxf(ty1 - fabsf(eyA - f1.y), 0.0f);
        const float px2 = fmaxf(tx2 - fabsf(exB - f2.x), 0.0f);
        const float py2 = fmaxf(ty2 - fabsf(eyB - f2.y), 0.0f);
        const float px3 = fmaxf(tx3 - fabsf(exB - f3.x), 0.0f);
        const float py3 = fmaxf(ty3 - fabsf(eyB - f3.y), 0.0f);
        acc += px0 * py0 + px1 * py1 + px2 * py2 + px3 * py3;
    }

    // ---- Block reduction: wave shuffle then LDS across 4 waves ----
    #pragma unroll
    for (int off = 32; off > 0; off >>= 1) acc += __shfl_down(acc, off);
    const int wave = tid >> 6;
    if ((tid & 63) == 0) s_part[wave] = acc;
    __syncthreads();

    // ---- Publish partial (agent scope) + completion counter ----
    if (tid == 0) {
        union { float2 f; unsigned long long u; } pk;
        pk.f = make_float2(s_part[0] + s_part[1] + s_part[2] + s_part[3], cnt);
        __hip_atomic_store(&ws_part[blockIdx.x], pk.u,
                           __ATOMIC_RELAXED, __HIP_MEMORY_SCOPE_AGENT);
        const int old = __hip_atomic_fetch_add(ws_flag, 1,
                           __ATOMIC_ACQ_REL, __HIP_MEMORY_SCOPE_AGENT);
        s_last = (old == (int)gridDim.x - 1);
    }
    __syncthreads();
    if (!s_last) return;

    // ---- Last block standing folds all partials ----
    float l = 0.0f, c = 0.0f;
    for (int i = tid; i < (int)gridDim.x; i += 256) {
        union { float2 f; unsigned long long u; } pk;
        pk.u = __hip_atomic_load(&ws_part[i],
                                 __ATOMIC_RELAXED, __HIP_MEMORY_SCOPE_AGENT);
        l += pk.f.x;
        c += pk.f.y;
    }
    #pragma unroll
    for (int off = 32; off > 0; off >>= 1) {
        l += __shfl_down(l, off);
        c += __shfl_down(c, off);
    }
    if ((tid & 63) == 0) { s_l[wave] = l; s_c[wave] = c; }
    __syncthreads();
    if (tid == 0) {
        const float L = s_l[0] + s_l[1] + s_l[2] + s_l[3];
        const float C = s_c[0] + s_c[1] + s_c[2] + s_c[3];
        out[0] = L / fmaxf(C, 1.0f);
    }
}

extern "C" void kernel_launch(void* const* d_in, const int* in_sizes, int n_in,
                              void* d_out, int out_size, void* d_ws, size_t ws_size,
                              hipStream_t stream)
{
    const float* pred_abs   = (const float*)d_in[0];
    const float* gt_bboxes  = (const float*)d_in[1];
    const int*   ego_masks  = (const int*)d_in[2];
    const int*   agent_mask = (const int*)d_in[3];
    float* out = (float*)d_out;

    const int B = in_sizes[0] / (T_DIM * 2);  // 4096
    const int grid = B / 2;                   // 2048 blocks, 2 batches each

    unsigned long long* ws_part = (unsigned long long*)d_ws;     // 16 KB
    int* ws_flag = (int*)((char*)d_ws + (size_t)grid * 8);       // own line

    // Counter must start at 0 every call (harness doesn't re-poison).
    hipMemsetAsync(ws_flag, 0, sizeof(int), stream);

    collision_loss_fused<<<dim3(grid), 256, 0, stream>>>(
        pred_abs, gt_bboxes, ego_masks, agent_mask, ws_part, ws_flag, out);
}

// Round 8
// 21.978 us; speedup vs baseline: 5.3028x; 5.3028x over previous
//
#include <hip/hip_runtime.h>

// CollisionLoss: loss = sum_{b,t,n} relu(tx[b,n] - |ex[b,t]-cx[b,n]|)
//                              * relu(ty[b,n] - |ey[b,t]-cy[b,n]|) * valid
//                / max(sum(ego_mask>=1), 1)
// pred_abs (B,T,2) f32, gt_bboxes (B,N,9) f32, ego_masks (B,T) i32,
// agent_mask (B,N) i32. B=4096, T=12, N=512.
//
// R1: same-address relaxed atomics ~12.5ns/op -> 153us. R7: same-address
// ACQ_REL RMW ~56ns/op -> 116us. Single-line cross-block sync is poison.
// R2-R4: 21-23us, main kernel insensitive to load structure.
// R8: mask-predicated bbox loads — invalid agents (~50%) skip their
// dwordx4+dword entirely (exec-masked lanes issue no transactions).
// Discriminates transaction-rate-bound (expect ~14-15us) vs
// line-bandwidth-bound (~18-19us) vs fixed wall (~21us).

#define T_DIM 12
#define N_DIM 512

typedef float f32x4 __attribute__((ext_vector_type(4)));

__global__ __launch_bounds__(256) void collision_loss_main(
    const float* __restrict__ pred_abs,   // (B,T,2)
    const float* __restrict__ gt_bboxes,  // (B,N,9)
    const int*   __restrict__ ego_masks,  // (B,T)
    const int*   __restrict__ agent_mask, // (B,N)
    float2* __restrict__ ws)              // (grid) {partial loss, ego count}
{
    __shared__ float s_ex[2][T_DIM];
    __shared__ float s_ey[2][T_DIM];
    __shared__ float s_part[4];

    const int b0  = blockIdx.x * 2;       // this block owns batches b0, b0+1
    const int tid = threadIdx.x;

    // ---- Ego staging (both batches); invalid ego -> +1e30 => term 0 ----
    int ev = 0;
    if (tid < 2 * T_DIM) {                // lanes 0..23 of wave 0
        const int bb = tid / T_DIM;
        const int t  = tid % T_DIM;
        const int b  = b0 + bb;
        ev = (ego_masks[b * T_DIM + t] >= 1) ? 1 : 0;
        const float ex = pred_abs[(b * T_DIM + t) * 2 + 0];
        const float ey = pred_abs[(b * T_DIM + t) * 2 + 1];
        s_ex[bb][t] = ev ? ex : 1e30f;
        s_ey[bb][t] = ev ? ey : 1e30f;
    }
    const float cnt = (float)__popcll(__ballot(ev != 0)); // wave-0 value used

    // ---- Masks first (coalesced), then predicated bbox loads ----
    const int* am = agent_mask + b0 * N_DIM;
    const int av0 = am[tid]       >= 1;
    const int av1 = am[tid + 256] >= 1;
    const int av2 = am[tid + 512] >= 1;
    const int av3 = am[tid + 768] >= 1;

    // Invalid agents contribute 0 (tx=-1e30); skip their loads entirely.
    // Exec-masked lanes issue no memory transactions.
    const float* base = gt_bboxes + (size_t)b0 * (N_DIM * 9);
    f32x4 f0 = {0.f, 0.f, 0.f, 0.f}; float g0 = 0.f;
    f32x4 f1 = {0.f, 0.f, 0.f, 0.f}; float g1 = 0.f;
    f32x4 f2 = {0.f, 0.f, 0.f, 0.f}; float g2 = 0.f;
    f32x4 f3 = {0.f, 0.f, 0.f, 0.f}; float g3 = 0.f;
    if (av0) {
        f0 = *(const f32x4*)(base + (size_t)(tid      ) * 9);
        g0 = base[(size_t)(tid      ) * 9 + 4];
    }
    if (av1) {
        f1 = *(const f32x4*)(base + (size_t)(tid + 256) * 9);
        g1 = base[(size_t)(tid + 256) * 9 + 4];
    }
    if (av2) {
        f2 = *(const f32x4*)(base + (size_t)(tid + 512) * 9);
        g2 = base[(size_t)(tid + 512) * 9 + 4];
    }
    if (av3) {
        f3 = *(const f32x4*)(base + (size_t)(tid + 768) * 9);
        g3 = base[(size_t)(tid + 768) * 9 + 4];
    }

    const float tx0 = av0 ? (1.175f + f0.w * 0.5f + 1.5f) : -1e30f;
    const float tx1 = av1 ? (1.175f + f1.w * 0.5f + 1.5f) : -1e30f;
    const float tx2 = av2 ? (1.175f + f2.w * 0.5f + 1.5f) : -1e30f;
    const float tx3 = av3 ? (1.175f + f3.w * 0.5f + 1.5f) : -1e30f;
    const float ty0 = 2.292f + g0 * 0.5f + 1.5f;
    const float ty1 = 2.292f + g1 * 0.5f + 1.5f;
    const float ty2 = 2.292f + g2 * 0.5f + 1.5f;
    const float ty3 = 2.292f + g3 * 0.5f + 1.5f;

    __syncthreads();   // ego staged

    float acc = 0.0f;
    #pragma unroll
    for (int t = 0; t < T_DIM; ++t) {
        const float exA = s_ex[0][t], eyA = s_ey[0][t];
        const float exB = s_ex[1][t], eyB = s_ey[1][t];
        const float px0 = fmaxf(tx0 - fabsf(exA - f0.x), 0.0f);
        const float py0 = fmaxf(ty0 - fabsf(eyA - f0.y), 0.0f);
        const float px1 = fmaxf(tx1 - fabsf(exA - f1.x), 0.0f);
        const float py1 = fmaxf(ty1 - fabsf(eyA - f1.y), 0.0f);
        const float px2 = fmaxf(tx2 - fabsf(exB - f2.x), 0.0f);
        const float py2 = fmaxf(ty2 - fabsf(eyB - f2.y), 0.0f);
        const float px3 = fmaxf(tx3 - fabsf(exB - f3.x), 0.0f);
        const float py3 = fmaxf(ty3 - fabsf(eyB - f3.y), 0.0f);
        acc += px0 * py0 + px1 * py1 + px2 * py2 + px3 * py3;
    }

    // ---- Block reduction: wave shuffle then LDS across 4 waves ----
    #pragma unroll
    for (int off = 32; off > 0; off >>= 1) acc += __shfl_down(acc, off);
    const int wave = tid >> 6;
    if ((tid & 63) == 0) s_part[wave] = acc;
    __syncthreads();
    if (tid == 0)
        ws[blockIdx.x] = make_float2(s_part[0] + s_part[1] + s_part[2] + s_part[3],
                                     cnt);
}

// Single-block reduce of nP float2 partials -> out[0].
__global__ __launch_bounds__(1024) void collision_loss_reduce(
    const float2* __restrict__ ws, float* __restrict__ out, int nP)
{
    __shared__ float s_l[16];
    __shared__ float s_c[16];
    const int tid = threadIdx.x;

    float l = 0.0f, c = 0.0f;
    for (int i = tid; i < nP; i += 1024) {
        const float2 v = ws[i];
        l += v.x;
        c += v.y;
    }
    #pragma unroll
    for (int off = 32; off > 0; off >>= 1) {
        l += __shfl_down(l, off);
        c += __shfl_down(c, off);
    }
    const int wave = tid >> 6;
    if ((tid & 63) == 0) { s_l[wave] = l; s_c[wave] = c; }
    __syncthreads();
    if (tid == 0) {
        float L = 0.0f, C = 0.0f;
        #pragma unroll
        for (int w = 0; w < 16; ++w) { L += s_l[w]; C += s_c[w]; }
        out[0] = L / fmaxf(C, 1.0f);
    }
}

extern "C" void kernel_launch(void* const* d_in, const int* in_sizes, int n_in,
                              void* d_out, int out_size, void* d_ws, size_t ws_size,
                              hipStream_t stream)
{
    const float* pred_abs   = (const float*)d_in[0];
    const float* gt_bboxes  = (const float*)d_in[1];
    const int*   ego_masks  = (const int*)d_in[2];
    const int*   agent_mask = (const int*)d_in[3];
    float* out = (float*)d_out;

    const int B = in_sizes[0] / (T_DIM * 2);  // 4096
    const int grid = B / 2;                   // 2048 blocks, 2 batches each

    float2* ws = (float2*)d_ws;

    collision_loss_main<<<dim3(grid), 256, 0, stream>>>(
        pred_abs, gt_bboxes, ego_masks, agent_mask, ws);

    collision_loss_reduce<<<dim3(1), 1024, 0, stream>>>(ws, out, grid);
}

// Round 9
// 21.887 us; speedup vs baseline: 5.3248x; 1.0041x over previous
//
#include <hip/hip_runtime.h>

// CollisionLoss: loss = sum_{b,t,n} relu(tx[b,n] - |ex[b,t]-cx[b,n]|)
//                              * relu(ty[b,n] - |ey[b,t]-cy[b,n]|) * valid
//                / max(sum(ego_mask>=1), 1)
// pred_abs (B,T,2) f32, gt_bboxes (B,N,9) f32, ego_masks (B,T) i32,
// agent_mask (B,N) i32. B=4096, T=12, N=512.
//
// Ledger: R1 same-address atomics 153us. R7 acq_rel RMW finisher 116us.
// R2/R3/R4/R8: four load structures all 21.0-22.8us -> main kernel is
// line-traffic-bound: 75.5MB irreducible 64B-line stream (36B rows leave
// no skippable line/sector) at ~4.5 TB/s LLC->L2 plateau ~= 17.5us.
// R9: single-variable A/B — main verbatim from R4 (21.0us best); reduce
// slimmed to 256 threads + float4 reads. Tests whether reduce-exec (~1.5us)
// or launch gaps dominate the non-main ~3.5us.

#define T_DIM 12
#define N_DIM 512

typedef float f32x4 __attribute__((ext_vector_type(4)));

__global__ __launch_bounds__(256) void collision_loss_main(
    const float* __restrict__ pred_abs,   // (B,T,2)
    const float* __restrict__ gt_bboxes,  // (B,N,9)
    const int*   __restrict__ ego_masks,  // (B,T)
    const int*   __restrict__ agent_mask, // (B,N)
    float2* __restrict__ ws)              // (grid) {partial loss, ego count}
{
    __shared__ float s_ex[2][T_DIM];
    __shared__ float s_ey[2][T_DIM];
    __shared__ float s_part[4];

    const int b0  = blockIdx.x * 2;       // this block owns batches b0, b0+1
    const int tid = threadIdx.x;

    // ---- Ego staging (both batches); invalid ego -> +1e30 => term 0 ----
    int ev = 0;
    if (tid < 2 * T_DIM) {                // lanes 0..23 of wave 0
        const int bb = tid / T_DIM;
        const int t  = tid % T_DIM;
        const int b  = b0 + bb;
        ev = (ego_masks[b * T_DIM + t] >= 1) ? 1 : 0;
        const float ex = pred_abs[(b * T_DIM + t) * 2 + 0];
        const float ey = pred_abs[(b * T_DIM + t) * 2 + 1];
        s_ex[bb][t] = ev ? ex : 1e30f;
        s_ey[bb][t] = ev ? ey : 1e30f;
    }
    const float cnt = (float)__popcll(__ballot(ev != 0)); // wave-0 value used

    // ---- 4 agents/thread: nontemporal dwordx4 + dword, issued upfront ----
    const float* base = gt_bboxes + (size_t)b0 * (N_DIM * 9);
    const f32x4 f0 = __builtin_nontemporal_load(
        (const f32x4*)(base + (size_t)(tid      ) * 9));
    const float g0 = __builtin_nontemporal_load(base + (size_t)(tid      ) * 9 + 4);
    const f32x4 f1 = __builtin_nontemporal_load(
        (const f32x4*)(base + (size_t)(tid + 256) * 9));
    const float g1 = __builtin_nontemporal_load(base + (size_t)(tid + 256) * 9 + 4);
    const f32x4 f2 = __builtin_nontemporal_load(
        (const f32x4*)(base + (size_t)(tid + 512) * 9));
    const float g2 = __builtin_nontemporal_load(base + (size_t)(tid + 512) * 9 + 4);
    const f32x4 f3 = __builtin_nontemporal_load(
        (const f32x4*)(base + (size_t)(tid + 768) * 9));
    const float g3 = __builtin_nontemporal_load(base + (size_t)(tid + 768) * 9 + 4);

    const int* am = agent_mask + b0 * N_DIM;
    const int av0 = __builtin_nontemporal_load(am + tid)       >= 1;
    const int av1 = __builtin_nontemporal_load(am + tid + 256) >= 1;
    const int av2 = __builtin_nontemporal_load(am + tid + 512) >= 1;
    const int av3 = __builtin_nontemporal_load(am + tid + 768) >= 1;

    // Invalid agent -> tx = -1e30 => relu term 0 (branch-free loop).
    const float tx0 = av0 ? (1.175f + f0.w * 0.5f + 1.5f) : -1e30f;
    const float tx1 = av1 ? (1.175f + f1.w * 0.5f + 1.5f) : -1e30f;
    const float tx2 = av2 ? (1.175f + f2.w * 0.5f + 1.5f) : -1e30f;
    const float tx3 = av3 ? (1.175f + f3.w * 0.5f + 1.5f) : -1e30f;
    const float ty0 = 2.292f + g0 * 0.5f + 1.5f;
    const float ty1 = 2.292f + g1 * 0.5f + 1.5f;
    const float ty2 = 2.292f + g2 * 0.5f + 1.5f;
    const float ty3 = 2.292f + g3 * 0.5f + 1.5f;

    __syncthreads();   // ego staged

    float acc = 0.0f;
    #pragma unroll
    for (int t = 0; t < T_DIM; ++t) {
        const float exA = s_ex[0][t], eyA = s_ey[0][t];
        const float exB = s_ex[1][t], eyB = s_ey[1][t];
        const float px0 = fmaxf(tx0 - fabsf(exA - f0.x), 0.0f);
        const float py0 = fmaxf(ty0 - fabsf(eyA - f0.y), 0.0f);
        const float px1 = fmaxf(tx1 - fabsf(exA - f1.x), 0.0f);
        const float py1 = fmaxf(ty1 - fabsf(eyA - f1.y), 0.0f);
        const float px2 = fmaxf(tx2 - fabsf(exB - f2.x), 0.0f);
        const float py2 = fmaxf(ty2 - fabsf(eyB - f2.y), 0.0f);
        const float px3 = fmaxf(tx3 - fabsf(exB - f3.x), 0.0f);
        const float py3 = fmaxf(ty3 - fabsf(eyB - f3.y), 0.0f);
        acc += px0 * py0 + px1 * py1 + px2 * py2 + px3 * py3;
    }

    // ---- Block reduction: wave shuffle then LDS across 4 waves ----
    #pragma unroll
    for (int off = 32; off > 0; off >>= 1) acc += __shfl_down(acc, off);
    const int wave = tid >> 6;
    if ((tid & 63) == 0) s_part[wave] = acc;
    __syncthreads();
    if (tid == 0)
        ws[blockIdx.x] = make_float2(s_part[0] + s_part[1] + s_part[2] + s_part[3],
                                     cnt);
}

// Slim finalize: 1 block x 256 threads, float4 reads of 2048 float2 = 16KB.
__global__ __launch_bounds__(256) void collision_loss_reduce(
    const float* __restrict__ ws, float* __restrict__ out, int nP)
{
    __shared__ float s_l[4];
    __shared__ float s_c[4];
    const int tid = threadIdx.x;

    // nP float2 = 2*nP floats; each f32x4 holds {l0,c0,l1,c1}.
    const f32x4* w4 = (const f32x4*)ws;
    const int n4 = nP / 2;                // 1024 f32x4 for nP=2048
    float l = 0.0f, c = 0.0f;
    #pragma unroll
    for (int i = tid; i < n4; i += 256) {
        const f32x4 v = w4[i];
        l += v.x + v.z;
        c += v.y + v.w;
    }
    #pragma unroll
    for (int off = 32; off > 0; off >>= 1) {
        l += __shfl_down(l, off);
        c += __shfl_down(c, off);
    }
    const int wave = tid >> 6;
    if ((tid & 63) == 0) { s_l[wave] = l; s_c[wave] = c; }
    __syncthreads();
    if (tid == 0) {
        const float L = s_l[0] + s_l[1] + s_l[2] + s_l[3];
        const float C = s_c[0] + s_c[1] + s_c[2] + s_c[3];
        out[0] = L / fmaxf(C, 1.0f);
    }
}

extern "C" void kernel_launch(void* const* d_in, const int* in_sizes, int n_in,
                              void* d_out, int out_size, void* d_ws, size_t ws_size,
                              hipStream_t stream)
{
    const float* pred_abs   = (const float*)d_in[0];
    const float* gt_bboxes  = (const float*)d_in[1];
    const int*   ego_masks  = (const int*)d_in[2];
    const int*   agent_mask = (const int*)d_in[3];
    float* out = (float*)d_out;

    const int B = in_sizes[0] / (T_DIM * 2);  // 4096
    const int grid = B / 2;                   // 2048 blocks, 2 batches each

    float2* ws = (float2*)d_ws;

    collision_loss_main<<<dim3(grid), 256, 0, stream>>>(
        pred_abs, gt_bboxes, ego_masks, agent_mask, ws);

    collision_loss_reduce<<<dim3(1), 256, 0, stream>>>((const float*)ws, out, grid);
}